// Round 8
// baseline (1397.140 us; speedup 1.0000x reference)
//
#include <hip/hip_runtime.h>
#include <math.h>

#define N_NODES 10000
#define N_EDGES 320000
#define IN_FEATS 512
#define N_UNITS 256
#define OUT_FEATS 64
#define N_HID 5  // hidden Wh layers

typedef __attribute__((ext_vector_type(8))) short bf16x8;
typedef __attribute__((ext_vector_type(4))) float f32x4;

__device__ __forceinline__ unsigned short f2bf(float f) {
    union { float f; unsigned int u; } c; c.f = f;
    unsigned int u = c.u + 0x7FFFu + ((c.u >> 16) & 1u);  // RNE
    return (unsigned short)(u >> 16);
}
__device__ __forceinline__ float bf2f(unsigned int b) {
    union { unsigned int u; float f; } c; c.u = (b & 0xffffu) << 16;
    return c.f;
}

struct MegaParams {
    const float* h; const int* src; const int* dst;
    const float* W0; const float* b0; const float* Wh; const float* bh;
    const float* Wo; const float* bo;
    int* deg; int* row_ptr; int* cursor; int* csr_src;
    float* dinv; float* invdeg;
    unsigned short* hb; unsigned short* W0t; unsigned short* Wht; unsigned short* Wot;
    unsigned short* m; unsigned short* x; unsigned short* jk; unsigned short* mf;
    float* out;
    unsigned int* bar;   // [0]=count, [1]=generation
};

// ---- grid barrier v2: RELAXED spin (no per-poll cache maintenance), single
// release fence on entry / acquire fence on exit. R5's acquire-in-loop emitted
// an L2 invalidate per poll (per-XCD L2 non-coherent) -> 125us/barrier. ----
__device__ __forceinline__ void gbar(unsigned int* bar, int nb) {
    __syncthreads();
    if (threadIdx.x == 0) {
        __builtin_amdgcn_fence(__ATOMIC_RELEASE, "agent");   // writeback my block's stores
        unsigned int g = __hip_atomic_load(&bar[1], __ATOMIC_RELAXED, __HIP_MEMORY_SCOPE_AGENT);
        unsigned int a = __hip_atomic_fetch_add(&bar[0], 1u, __ATOMIC_ACQ_REL, __HIP_MEMORY_SCOPE_AGENT);
        if (a == (unsigned int)nb - 1u) {
            __hip_atomic_store(&bar[0], 0u, __ATOMIC_RELAXED, __HIP_MEMORY_SCOPE_AGENT);
            __hip_atomic_store(&bar[1], g + 1u, __ATOMIC_RELEASE, __HIP_MEMORY_SCOPE_AGENT);
        } else {
            while (__hip_atomic_load(&bar[1], __ATOMIC_RELAXED, __HIP_MEMORY_SCOPE_AGENT) == g)
                __builtin_amdgcn_s_sleep(2);
        }
        __builtin_amdgcn_fence(__ATOMIC_ACQUIRE, "agent");   // one L1/L2 invalidate per barrier
    }
    __syncthreads();
}

// ---- single-block scan (256 threads x 40 elems); validated in R5 ----
__device__ void scan_dev(const int* __restrict__ deg, int* __restrict__ row_ptr,
                         int* __restrict__ cursor, float* __restrict__ dinv,
                         float* __restrict__ invdeg, int* wsum) {
    const int PER = 40;
    int t = threadIdx.x, lane = t & 63, w = t >> 6;
    int base = t * PER;
    int v[PER];
    int s = 0;
#pragma unroll
    for (int j = 0; j < PER; ++j) {
        int i = base + j;
        int d = (i < N_NODES) ? deg[i] : 0;
        v[j] = s; s += d;
    }
    int inc = s;
#pragma unroll
    for (int off = 1; off < 64; off <<= 1) {
        int y = __shfl_up(inc, off);
        if (lane >= off) inc += y;
    }
    if (lane == 63) wsum[w] = inc;
    __syncthreads();
    if (t == 0) {
        int c = 0;
#pragma unroll
        for (int k = 0; k < 4; ++k) { int tmp = wsum[k]; wsum[k] = c; c += tmp; }
    }
    __syncthreads();
    int texcl = wsum[w] + (inc - s);
#pragma unroll
    for (int j = 0; j < PER; ++j) {
        int i = base + j;
        if (i < N_NODES) {
            int rp = texcl + v[j];
            row_ptr[i] = rp;
            cursor[i]  = rp;
            int d = ((j + 1 < PER) ? v[j + 1] : s) - v[j];
            float dd = (float)(d + 1);
            dinv[i]   = rsqrtf(dd);
            invdeg[i] = 1.0f / dd;
        }
    }
    if (t == 255) row_ptr[N_NODES] = texcl + s;
}

// ---- BN=64 dbuf MFMA GEMM over grid-strided tiles (16 KB LDS) ----
__device__ void gemm_dev(const unsigned short* __restrict__ A,
                         const unsigned short* __restrict__ Bt,
                         unsigned short* __restrict__ C,
                         const int M, const int K, const int Nld,
                         const int tile0, const int tstride,
                         unsigned short* As, unsigned short* Bs) {
    constexpr int BM = 64, BN = 64, BK = 32;
    constexpr int BUF = BM * BK;  // shorts per buffer

    const int tid = threadIdx.x;
    const int wid = tid >> 6, lane = tid & 63;
    const int wr = wid >> 1, wc = wid & 1;
    const int lr = lane & 15, lk = lane >> 4;
    const int ntm = (M + BM - 1) / BM;
    const int ntiles = ntm * (Nld / BN);

    const int row  = tid >> 2;
    const int slot = tid & 3;
    const int sslot = slot ^ ((row >> 1) & 3);

    for (int tile = tile0; tile < ntiles; tile += tstride) {
        const int brow = (tile % ntm) * BM;
        const int bcol = (tile / ntm) * BN;

        int gra = brow + row; if (gra >= M) gra = M - 1;
        const unsigned short* gpa = A + (size_t)gra * K + sslot * 8;
        const unsigned short* gpb = Bt + (size_t)(bcol + row) * K + sslot * 8;

        f32x4 acc[2][2];
#pragma unroll
        for (int m = 0; m < 2; ++m)
#pragma unroll
            for (int n = 0; n < 2; ++n)
                acc[m][n] = (f32x4){0.f, 0.f, 0.f, 0.f};

#define STAGE(buf, k0)                                                                        \
    do {                                                                                      \
        __builtin_amdgcn_global_load_lds(                                                     \
            (const __attribute__((address_space(1))) void*)(gpa + (k0)),                      \
            (__attribute__((address_space(3))) void*)(As + (buf) * BUF + tid * 8), 16, 0, 0); \
        __builtin_amdgcn_global_load_lds(                                                     \
            (const __attribute__((address_space(1))) void*)(gpb + (k0)),                      \
            (__attribute__((address_space(3))) void*)(Bs + (buf) * BUF + tid * 8), 16, 0, 0); \
    } while (0)

        STAGE(0, 0);
        __syncthreads();

        const int nk = K / BK;
        for (int kt = 0; kt < nk; ++kt) {
            const int cur = kt & 1;
            if (kt + 1 < nk) STAGE(cur ^ 1, (kt + 1) * BK);

            bf16x8 af[2], bfr[2];
#pragma unroll
            for (int m = 0; m < 2; ++m) {
                int ra = wr * 32 + m * 16 + lr;
                af[m] = *(const bf16x8*)(As + cur * BUF + ra * BK + ((lk ^ ((ra >> 1) & 3)) * 8));
            }
#pragma unroll
            for (int n = 0; n < 2; ++n) {
                int rb = wc * 32 + n * 16 + lr;
                bfr[n] = *(const bf16x8*)(Bs + cur * BUF + rb * BK + ((lk ^ ((rb >> 1) & 3)) * 8));
            }
#pragma unroll
            for (int m = 0; m < 2; ++m)
#pragma unroll
                for (int n = 0; n < 2; ++n)
                    acc[m][n] = __builtin_amdgcn_mfma_f32_16x16x32_bf16(af[m], bfr[n], acc[m][n], 0, 0, 0);
            __syncthreads();
        }
#undef STAGE

#pragma unroll
        for (int m = 0; m < 2; ++m)
#pragma unroll
            for (int r = 0; r < 4; ++r) {
                int orow = brow + wr * 32 + m * 16 + lk * 4 + r;
                if (orow < M) {
#pragma unroll
                    for (int n = 0; n < 2; ++n) {
                        int ocol = bcol + wc * 32 + n * 16 + lr;
                        C[(size_t)orow * Nld + ocol] = f2bf(acc[m][n][r]);
                    }
                }
            }
        __syncthreads();  // As/Bs reusable for next tile
    }
}

// ---- CSR agg + bias + relu + running JK max; L2-split halves (R7-validated) ----
__device__ void agg_dev(const unsigned short* __restrict__ m,
                        const int* __restrict__ row_ptr, const int* __restrict__ csr_src,
                        const float* __restrict__ bias,
                        unsigned short* __restrict__ x_out, unsigned short* __restrict__ jk,
                        int init_jk, int bid, int nb) {
    const int nib  = threadIdx.x >> 4;
    const int lane = threadIdx.x & 15;
    const uint4* mv = (const uint4*)m;

    for (int vb = bid; vb < 1250; vb += nb) {
        const int halfsel = (vb >= 625) ? 1 : 0;
        const int g = vb - halfsel * 625;
        const int n = g * 16 + nib;
        const int s = row_ptr[n], e = row_ptr[n + 1];
        const int off = halfsel * 16 + lane;

        float a[8];
#pragma unroll
        for (int j = 0; j < 8; ++j) a[j] = 0.f;

#define ACC8(u)                                        \
    do {                                               \
        a[0] += bf2f((u).x); a[1] += bf2f((u).x >> 16);\
        a[2] += bf2f((u).y); a[3] += bf2f((u).y >> 16);\
        a[4] += bf2f((u).z); a[5] += bf2f((u).z >> 16);\
        a[6] += bf2f((u).w); a[7] += bf2f((u).w >> 16);\
    } while (0)

        int i = s;
        for (; i + 3 < e; i += 4) {
            int s0 = csr_src[i], s1 = csr_src[i + 1], s2 = csr_src[i + 2], s3 = csr_src[i + 3];
            uint4 u0 = mv[(size_t)s0 * 32 + off];
            uint4 u1 = mv[(size_t)s1 * 32 + off];
            uint4 u2 = mv[(size_t)s2 * 32 + off];
            uint4 u3 = mv[(size_t)s3 * 32 + off];
            ACC8(u0); ACC8(u1); ACC8(u2); ACC8(u3);
        }
        for (; i < e; ++i) {
            uint4 u = mv[(size_t)csr_src[i] * 32 + off];
            ACC8(u);
        }
#undef ACC8

        float4 b0 = ((const float4*)bias)[halfsel * 32 + lane * 2];
        float4 b1 = ((const float4*)bias)[halfsel * 32 + lane * 2 + 1];
        unsigned int hh[8];
        hh[0] = f2bf(fmaxf(a[0] + b0.x, 0.f));
        hh[1] = f2bf(fmaxf(a[1] + b0.y, 0.f));
        hh[2] = f2bf(fmaxf(a[2] + b0.z, 0.f));
        hh[3] = f2bf(fmaxf(a[3] + b0.w, 0.f));
        hh[4] = f2bf(fmaxf(a[4] + b1.x, 0.f));
        hh[5] = f2bf(fmaxf(a[5] + b1.y, 0.f));
        hh[6] = f2bf(fmaxf(a[6] + b1.z, 0.f));
        hh[7] = f2bf(fmaxf(a[7] + b1.w, 0.f));
        uint4 o;
        o.x = hh[0] | (hh[1] << 16);
        o.y = hh[2] | (hh[3] << 16);
        o.z = hh[4] | (hh[5] << 16);
        o.w = hh[6] | (hh[7] << 16);

        size_t idx = (size_t)n * 32 + off;
        ((uint4*)x_out)[idx] = o;
        if (init_jk) {
            ((uint4*)jk)[idx] = o;
        } else {
            uint4 j = ((const uint4*)jk)[idx];
            auto mx2 = [](unsigned int nw, unsigned int od) {
                unsigned int lo_n = nw & 0xffffu, lo_o = od & 0xffffu;
                unsigned int hi_n = nw >> 16,     hi_o = od >> 16;
                unsigned int lo = lo_n > lo_o ? lo_n : lo_o;
                unsigned int hi = hi_n > hi_o ? hi_n : hi_o;
                return lo | (hi << 16);
            };
            uint4 w;
            w.x = mx2(o.x, j.x); w.y = mx2(o.y, j.y);
            w.z = mx2(o.z, j.z); w.w = mx2(o.w, j.w);
            ((uint4*)jk)[idx] = w;
        }
    }
}

// ---- the mega kernel ----
__global__ __launch_bounds__(256, 4) void k_mega(MegaParams P) {
    __shared__ __align__(16) unsigned short AS[2 * 64 * 32];
    __shared__ __align__(16) unsigned short BS[2 * 64 * 32];
    __shared__ int wsum[4];
    const int nb = gridDim.x;
    const int bid = blockIdx.x;
    const int tid = threadIdx.x;
    const int gtid = bid * 256 + tid;
    const int NT = nb * 256;

    // P0: edge histogram (deg pre-zeroed by memset) + h->bf16 + weights->bf16^T
    {
        const int R1 = N_EDGES;
        const int R2 = N_NODES * IN_FEATS / 4;
        const int S0 = IN_FEATS * N_UNITS;
        const int SH = N_HID * N_UNITS * N_UNITS;
        const int SO = N_UNITS * OUT_FEATS;
        const int TOT = R1 + R2 + S0 + SH + SO;
        for (int t = gtid; t < TOT; t += NT) {
            if (t < R1) {
                atomicAdd(&P.deg[P.dst[t]], 1);
            } else if (t < R1 + R2) {
                int u = t - R1;
                float4 v = reinterpret_cast<const float4*>(P.h)[u];
                ushort4 o;
                o.x = f2bf(v.x); o.y = f2bf(v.y); o.z = f2bf(v.z); o.w = f2bf(v.w);
                reinterpret_cast<ushort4*>(P.hb)[u] = o;
            } else {
                int u = t - R1 - R2;
                if (u < S0) {
                    int k = u >> 8, n = u & 255;
                    P.W0t[(size_t)n * IN_FEATS + k] = f2bf(P.W0[u]);
                } else if (u < S0 + SH) {
                    int w = u - S0;
                    int l = w >> 16, r = w & 65535;
                    int k = r >> 8, n = r & 255;
                    P.Wht[(size_t)l * 65536 + (size_t)n * N_UNITS + k] = f2bf(P.Wh[w]);
                } else {
                    int w = u - S0 - SH;
                    int k = w >> 6, n = w & 63;
                    P.Wot[(size_t)n * N_UNITS + k] = f2bf(P.Wo[w]);
                }
            }
        }
    }
    gbar(P.bar, nb);

    // P1: scan (block 0) overlapped with layer-0 GEMM (remaining blocks)
    if (bid == 0) {
        scan_dev(P.deg, P.row_ptr, P.cursor, P.dinv, P.invdeg, wsum);
    } else {
        gemm_dev(P.hb, P.W0t, P.m, N_NODES, IN_FEATS, N_UNITS,
                 bid - 1, nb - 1, AS, BS);
    }
    gbar(P.bar, nb);

    // P2: CSR fill
    for (int e = gtid; e < N_EDGES; e += NT) {
        int p = atomicAdd(&P.cursor[P.dst[e]], 1);
        P.csr_src[p] = P.src[e];
    }
    gbar(P.bar, nb);

    // P3: agg layer 0 (init jk)
    agg_dev(P.m, P.row_ptr, P.csr_src, P.b0, P.x, P.jk, 1, bid, nb);
    gbar(P.bar, nb);

    // hidden layers
    for (int l = 0; l < N_HID; ++l) {
        gemm_dev(P.x, P.Wht + (size_t)l * 65536, P.m, N_NODES, N_UNITS, N_UNITS,
                 bid, nb, AS, BS);
        gbar(P.bar, nb);
        agg_dev(P.m, P.row_ptr, P.csr_src, P.bh + (size_t)l * N_UNITS, P.x, P.jk, 0, bid, nb);
        gbar(P.bar, nb);
    }

    // final GEMM: mf = jk @ Wot^T
    gemm_dev(P.jk, P.Wot, P.mf, N_NODES, N_UNITS, OUT_FEATS, bid, nb, AS, BS);
    gbar(P.bar, nb);

    // P-last: GCN-norm agg + self-loop + bias + log_softmax (2 nodes/wave)
    {
        int halfw = tid >> 5;
        int wl = tid & 31;
        const unsigned int* mfu = (const unsigned int*)P.mf;
        for (int g = bid; g < N_NODES / 8; g += nb) {
            int n = g * 8 + halfw;
            int s = P.row_ptr[n], e = P.row_ptr[n + 1];
            float a0 = 0.f, a1 = 0.f;
            int i = s;
            for (; i + 1 < e; i += 2) {
                int s0 = P.csr_src[i], s1 = P.csr_src[i + 1];
                unsigned int u0 = mfu[(size_t)s0 * 32 + wl];
                unsigned int u1 = mfu[(size_t)s1 * 32 + wl];
                float d0 = P.dinv[s0], d1 = P.dinv[s1];
                a0 += bf2f(u0) * d0 + bf2f(u1) * d1;
                a1 += bf2f(u0 >> 16) * d0 + bf2f(u1 >> 16) * d1;
            }
            for (; i < e; ++i) {
                int sr = P.csr_src[i];
                unsigned int u = mfu[(size_t)sr * 32 + wl];
                float dv = P.dinv[sr];
                a0 += bf2f(u) * dv;
                a1 += bf2f(u >> 16) * dv;
            }
            float dn = P.dinv[n];
            a0 *= dn; a1 *= dn;
            unsigned int un = mfu[(size_t)n * 32 + wl];
            float idg = P.invdeg[n];
            float2 bo2 = ((const float2*)P.bo)[wl];
            a0 += bf2f(un) * idg + bo2.x;
            a1 += bf2f(un >> 16) * idg + bo2.y;

            float mx = fmaxf(a0, a1);
#pragma unroll
            for (int off = 16; off; off >>= 1) mx = fmaxf(mx, __shfl_xor(mx, off));
            float e0 = __expf(a0 - mx), e1 = __expf(a1 - mx);
            float sum = e0 + e1;
#pragma unroll
            for (int off = 16; off; off >>= 1) sum += __shfl_xor(sum, off);
            float ls = __logf(sum);
            float2 r;
            r.x = a0 - mx - ls;
            r.y = a1 - mx - ls;
            ((float2*)P.out)[(size_t)n * 32 + wl] = r;
        }
    }
}

// ---------------- launch ----------------

extern "C" void kernel_launch(void* const* d_in, const int* in_sizes, int n_in,
                              void* d_out, int out_size, void* d_ws, size_t ws_size,
                              hipStream_t stream) {
    const float* h  = (const float*)d_in[0];
    const int*   ei = (const int*)d_in[1];
    const float* W0 = (const float*)d_in[2];
    const float* b0 = (const float*)d_in[3];
    const float* Wh = (const float*)d_in[4];
    const float* bh = (const float*)d_in[5];
    const float* Wo = (const float*)d_in[6];
    const float* bo = (const float*)d_in[7];

    char* p = (char*)d_ws;
    auto carve = [&](size_t bytes) {
        char* r = p;
        p += (bytes + 255) & ~(size_t)255;
        return r;
    };
    unsigned int* bar = (unsigned int*)carve(8);       // barrier state (zeroed below)
    int*   deg     = (int*)  carve(N_NODES * 4);       // contiguous after bar for one memset
    int*   row_ptr = (int*)  carve((N_NODES + 1) * 4);
    int*   cursor  = (int*)  carve(N_NODES * 4);
    int*   csr_src = (int*)  carve(N_EDGES * 4);
    float* dinv    = (float*)carve(N_NODES * 4);
    float* invdeg  = (float*)carve(N_NODES * 4);
    unsigned short* hb  = (unsigned short*)carve((size_t)N_NODES * IN_FEATS * 2);
    unsigned short* W0t = (unsigned short*)carve((size_t)IN_FEATS * N_UNITS * 2);
    unsigned short* Wht = (unsigned short*)carve((size_t)N_HID * N_UNITS * N_UNITS * 2);
    unsigned short* Wot = (unsigned short*)carve((size_t)N_UNITS * OUT_FEATS * 2);
    unsigned short* m   = (unsigned short*)carve((size_t)N_NODES * N_UNITS * 2);
    unsigned short* x   = (unsigned short*)carve((size_t)N_NODES * N_UNITS * 2);
    unsigned short* jk  = (unsigned short*)carve((size_t)N_NODES * N_UNITS * 2);
    unsigned short* mf  = (unsigned short*)carve((size_t)N_NODES * OUT_FEATS * 2);

    size_t zlen = (size_t)((char*)(deg + N_NODES) - (char*)bar);
    hipMemsetAsync(bar, 0, zlen, stream);

    MegaParams mp;
    mp.h = h; mp.src = ei; mp.dst = ei + N_EDGES;
    mp.W0 = W0; mp.b0 = b0; mp.Wh = Wh; mp.bh = bh; mp.Wo = Wo; mp.bo = bo;
    mp.deg = deg; mp.row_ptr = row_ptr; mp.cursor = cursor; mp.csr_src = csr_src;
    mp.dinv = dinv; mp.invdeg = invdeg;
    mp.hb = hb; mp.W0t = W0t; mp.Wht = Wht; mp.Wot = Wot;
    mp.m = m; mp.x = x; mp.jk = jk; mp.mf = mf;
    mp.out = (float*)d_out; mp.bar = bar;

    int maxb = 0;
    hipOccupancyMaxActiveBlocksPerMultiprocessor(&maxb, k_mega, 256, 0);
    if (maxb < 1) maxb = 1;
    if (maxb > 4) maxb = 4;
    int grid = maxb * 256;   // co-resident by construction (cooperative launch checks too)

    void* args[] = { &mp };
    hipLaunchCooperativeKernel((const void*)k_mega, dim3(grid), dim3(256), args, 0, stream);
}

// Round 9
// 346.807 us; speedup vs baseline: 4.0286x; 4.0286x over previous
//
#include <hip/hip_runtime.h>
#include <math.h>

#define N_NODES 10000
#define N_EDGES 320000
#define IN_FEATS 512
#define N_UNITS 256
#define OUT_FEATS 64
#define N_HID 5  // hidden Wh layers

typedef __attribute__((ext_vector_type(8))) short bf16x8;
typedef __attribute__((ext_vector_type(4))) float f32x4;

__device__ __forceinline__ unsigned short f2bf(float f) {
    union { float f; unsigned int u; } c; c.f = f;
    unsigned int u = c.u + 0x7FFFu + ((c.u >> 16) & 1u);  // RNE
    return (unsigned short)(u >> 16);
}
__device__ __forceinline__ float bf2f(unsigned int b) {
    union { unsigned int u; float f; } c; c.u = (b & 0xffffu) << 16;
    return c.f;
}

// ---------------- fused setup: deg histogram + h->bf16 + weights->bf16 transposed ----------------

__global__ void k_setup(const int* __restrict__ dst, int* __restrict__ deg,
                        const float* __restrict__ h, unsigned short* __restrict__ hb,
                        const float* __restrict__ W0, const float* __restrict__ Wh,
                        const float* __restrict__ Wo,
                        unsigned short* __restrict__ W0t, unsigned short* __restrict__ Wht,
                        unsigned short* __restrict__ Wot) {
    const int R1 = N_EDGES;
    const int R2 = N_NODES * IN_FEATS / 4;
    const int S0 = IN_FEATS * N_UNITS;
    const int SH = N_HID * N_UNITS * N_UNITS;
    const int SO = N_UNITS * OUT_FEATS;
    int t = blockIdx.x * blockDim.x + threadIdx.x;
    if (t < R1) {
        atomicAdd(&deg[dst[t]], 1);
    } else if (t < R1 + R2) {
        int u = t - R1;
        float4 v = reinterpret_cast<const float4*>(h)[u];
        ushort4 o;
        o.x = f2bf(v.x); o.y = f2bf(v.y); o.z = f2bf(v.z); o.w = f2bf(v.w);
        reinterpret_cast<ushort4*>(hb)[u] = o;
    } else {
        int u = t - R1 - R2;
        if (u < S0) {
            int k = u >> 8, n = u & 255;
            W0t[(size_t)n * IN_FEATS + k] = f2bf(W0[u]);
        } else if (u < S0 + SH) {
            int w = u - S0;
            int l = w >> 16, r = w & 65535;
            int k = r >> 8, n = r & 255;
            Wht[(size_t)l * 65536 + (size_t)n * N_UNITS + k] = f2bf(Wh[w]);
        } else if (u < S0 + SH + SO) {
            int w = u - S0 - SH;
            int k = w >> 6, n = w & 63;
            Wot[(size_t)n * N_UNITS + k] = f2bf(Wo[w]);
        }
    }
}

// ---------------- scan: one 1024-thread block, 10/thread, 3 barriers ----------------

__global__ __launch_bounds__(1024) void k_scan(const int* __restrict__ deg,
                                               int* __restrict__ row_ptr,
                                               int* __restrict__ cursor,
                                               float* __restrict__ dinv,
                                               float* __restrict__ invdeg) {
    __shared__ int wsum[16];
    const int PER = 10;
    int t = threadIdx.x;
    int lane = t & 63, wid = t >> 6;
    int base = t * PER;

    int v[PER];
    int s = 0;
#pragma unroll
    for (int j = 0; j < PER; ++j) {
        int i = base + j;
        int d = (i < N_NODES) ? deg[i] : 0;
        v[j] = s;
        s += d;
    }
    int inc = s;
#pragma unroll
    for (int off = 1; off < 64; off <<= 1) {
        int y = __shfl_up(inc, off);
        if (lane >= off) inc += y;
    }
    if (lane == 63) wsum[wid] = inc;
    __syncthreads();
    if (wid == 0) {
        int w = (lane < 16) ? wsum[lane] : 0;
#pragma unroll
        for (int off = 1; off < 16; off <<= 1) {
            int y = __shfl_up(w, off);
            if (lane >= off) w += y;
        }
        if (lane < 16) wsum[lane] = w;
    }
    __syncthreads();
    int wave_excl = (wid == 0) ? 0 : wsum[wid - 1];
    int thread_excl = wave_excl + (inc - s);

#pragma unroll
    for (int j = 0; j < PER; ++j) {
        int i = base + j;
        if (i < N_NODES) {
            int rp = thread_excl + v[j];
            row_ptr[i] = rp;
            cursor[i]  = rp;
            int d = ((j + 1 < PER) ? v[j + 1] : s) - v[j];
            float dd = (float)(d + 1);
            dinv[i]   = rsqrtf(dd);
            invdeg[i] = 1.0f / dd;
        }
    }
    if (t == 1023) row_ptr[N_NODES] = thread_excl + s;
}

__global__ void k_fill(const int* __restrict__ src, const int* __restrict__ dst,
                       int* __restrict__ cursor, int* __restrict__ csr_src) {
    int e = blockIdx.x * blockDim.x + threadIdx.x;
    if (e < N_EDGES) {
        int p = atomicAdd(&cursor[dst[e]], 1);
        csr_src[p] = src[e];
    }
}

// ---------------- fused layer 0: x1 = relu(agg(h)@W0^T + b0), jk init ----------------
// agg(x@W) == agg(x)@W. 8 nodes/block; gather h (K=512) into LDS; MFMA u@W0t; epilogue.
// LDS swizzle: 16B slot ^ (row&7) on both write and read (self-consistent pair).

__global__ __launch_bounds__(256) void k_l0(const unsigned short* __restrict__ hb,
                                            const int* __restrict__ row_ptr,
                                            const int* __restrict__ csr_src,
                                            const unsigned short* __restrict__ W0t,
                                            const float* __restrict__ b0,
                                            unsigned short* __restrict__ x_out,
                                            unsigned short* __restrict__ jk) {
    constexpr int K = IN_FEATS;  // 512
    __shared__ unsigned short U[16 * K];  // 16 KB, rows 8..15 zero

    const int tid = threadIdx.x;
    const int tg = tid >> 5, sl = tid & 31;

    {   // zero pad rows 8..15 (linear; zeros are swizzle-invariant)
        uint4 z4 = {0u, 0u, 0u, 0u};
        ((uint4*)(U + 8 * K))[tid] = z4;
        ((uint4*)(U + 8 * K))[tid + 256] = z4;
    }

    const int n = blockIdx.x * 8 + tg;
    const int s = row_ptr[n], e = row_ptr[n + 1];
    const uint4* hv = (const uint4*)hb;  // 64 uint4 per row

    float a[16];
#pragma unroll
    for (int j = 0; j < 16; ++j) a[j] = 0.f;

#define ACCL(u, base)                                                        \
    do {                                                                     \
        a[base + 0] += bf2f((u).x); a[base + 1] += bf2f((u).x >> 16);        \
        a[base + 2] += bf2f((u).y); a[base + 3] += bf2f((u).y >> 16);        \
        a[base + 4] += bf2f((u).z); a[base + 5] += bf2f((u).z >> 16);        \
        a[base + 6] += bf2f((u).w); a[base + 7] += bf2f((u).w >> 16);        \
    } while (0)

    int i = s;
    for (; i + 1 < e; i += 2) {
        int s0 = csr_src[i], s1 = csr_src[i + 1];
        uint4 u0 = hv[(size_t)s0 * 64 + sl];
        uint4 u1 = hv[(size_t)s0 * 64 + 32 + sl];
        uint4 u2 = hv[(size_t)s1 * 64 + sl];
        uint4 u3 = hv[(size_t)s1 * 64 + 32 + sl];
        ACCL(u0, 0); ACCL(u1, 8); ACCL(u2, 0); ACCL(u3, 8);
    }
    for (; i < e; ++i) {
        int sr = csr_src[i];
        uint4 u0 = hv[(size_t)sr * 64 + sl];
        uint4 u1 = hv[(size_t)sr * 64 + 32 + sl];
        ACCL(u0, 0); ACCL(u1, 8);
    }
#undef ACCL

    uint4 o0, o1;
    o0.x = f2bf(a[0]) | ((unsigned)f2bf(a[1]) << 16);
    o0.y = f2bf(a[2]) | ((unsigned)f2bf(a[3]) << 16);
    o0.z = f2bf(a[4]) | ((unsigned)f2bf(a[5]) << 16);
    o0.w = f2bf(a[6]) | ((unsigned)f2bf(a[7]) << 16);
    o1.x = f2bf(a[8]) | ((unsigned)f2bf(a[9]) << 16);
    o1.y = f2bf(a[10]) | ((unsigned)f2bf(a[11]) << 16);
    o1.z = f2bf(a[12]) | ((unsigned)f2bf(a[13]) << 16);
    o1.w = f2bf(a[14]) | ((unsigned)f2bf(a[15]) << 16);
    ((uint4*)U)[tg * 64 + (sl ^ tg)] = o0;
    ((uint4*)U)[tg * 64 + ((32 + sl) ^ tg)] = o1;
    __syncthreads();

    // GEMM: 4 waves; wave w covers cols [w*64, w*64+64); A rows 0..15 (8 real)
    const int wid = tid >> 6, lane = tid & 63;
    const int lr = lane & 15, lk = lane >> 4;
    const unsigned short* Urow = U + lr * K;
    const int ex = lr & 7;

    f32x4 acc[4];
#pragma unroll
    for (int n4 = 0; n4 < 4; ++n4) acc[n4] = (f32x4){0.f, 0.f, 0.f, 0.f};

#pragma unroll
    for (int kk = 0; kk < K / 32; ++kk) {
        bf16x8 av = *(const bf16x8*)(Urow + ((((kk << 2) + lk)) ^ ex) * 8);
#pragma unroll
        for (int n4 = 0; n4 < 4; ++n4) {
            const unsigned short* brow =
                W0t + (size_t)(wid * 64 + n4 * 16 + lr) * K + kk * 32 + lk * 8;
            bf16x8 bv = *(const bf16x8*)brow;
            acc[n4] = __builtin_amdgcn_mfma_f32_16x16x32_bf16(av, bv, acc[n4], 0, 0, 0);
        }
    }

    if (lk < 2) {  // rows 0..7 only
#pragma unroll
        for (int n4 = 0; n4 < 4; ++n4) {
            int col = wid * 64 + n4 * 16 + lr;
            float bb = b0[col];
#pragma unroll
            for (int rr = 0; rr < 4; ++rr) {
                int node = blockIdx.x * 8 + (lk << 2) + rr;
                unsigned short v = f2bf(fmaxf(acc[n4][rr] + bb, 0.f));
                size_t idx = (size_t)node * N_UNITS + col;
                x_out[idx] = v;
                jk[idx] = v;
            }
        }
    }
}

// ---------------- fused hidden layer: x_out = relu(agg(x_in)@W^T + b), jk = max ----------------

__global__ __launch_bounds__(256) void k_lh(const unsigned short* __restrict__ x_in,
                                            const int* __restrict__ row_ptr,
                                            const int* __restrict__ csr_src,
                                            const unsigned short* __restrict__ Wt,
                                            const float* __restrict__ bias,
                                            unsigned short* __restrict__ x_out,
                                            unsigned short* __restrict__ jk) {
    constexpr int K = N_UNITS;  // 256
    __shared__ unsigned short U[16 * K];  // 8 KB

    const int tid = threadIdx.x;
    const int tg = tid >> 5, sl = tid & 31;

    {   // zero pad rows 8..15
        uint4 z4 = {0u, 0u, 0u, 0u};
        ((uint4*)(U + 8 * K))[tid] = z4;  // 256 uint4 = 2048 shorts
    }

    const int n = blockIdx.x * 8 + tg;
    const int s = row_ptr[n], e = row_ptr[n + 1];
    const uint4* xv = (const uint4*)x_in;  // 32 uint4 per row

    float a[8];
#pragma unroll
    for (int j = 0; j < 8; ++j) a[j] = 0.f;

#define ACC8(u)                                        \
    do {                                               \
        a[0] += bf2f((u).x); a[1] += bf2f((u).x >> 16);\
        a[2] += bf2f((u).y); a[3] += bf2f((u).y >> 16);\
        a[4] += bf2f((u).z); a[5] += bf2f((u).z >> 16);\
        a[6] += bf2f((u).w); a[7] += bf2f((u).w >> 16);\
    } while (0)

    int i = s;
    for (; i + 3 < e; i += 4) {
        uint4 u0 = xv[(size_t)csr_src[i + 0] * 32 + sl];
        uint4 u1 = xv[(size_t)csr_src[i + 1] * 32 + sl];
        uint4 u2 = xv[(size_t)csr_src[i + 2] * 32 + sl];
        uint4 u3 = xv[(size_t)csr_src[i + 3] * 32 + sl];
        ACC8(u0); ACC8(u1); ACC8(u2); ACC8(u3);
    }
    for (; i < e; ++i) {
        uint4 u = xv[(size_t)csr_src[i] * 32 + sl];
        ACC8(u);
    }
#undef ACC8

    uint4 o0;
    o0.x = f2bf(a[0]) | ((unsigned)f2bf(a[1]) << 16);
    o0.y = f2bf(a[2]) | ((unsigned)f2bf(a[3]) << 16);
    o0.z = f2bf(a[4]) | ((unsigned)f2bf(a[5]) << 16);
    o0.w = f2bf(a[6]) | ((unsigned)f2bf(a[7]) << 16);
    ((uint4*)U)[tg * 32 + (sl ^ tg)] = o0;
    __syncthreads();

    const int wid = tid >> 6, lane = tid & 63;
    const int lr = lane & 15, lk = lane >> 4;
    const unsigned short* Urow = U + lr * K;
    const int ex = lr & 7;

    f32x4 acc[4];
#pragma unroll
    for (int n4 = 0; n4 < 4; ++n4) acc[n4] = (f32x4){0.f, 0.f, 0.f, 0.f};

#pragma unroll
    for (int kk = 0; kk < K / 32; ++kk) {
        bf16x8 av = *(const bf16x8*)(Urow + ((((kk << 2) + lk)) ^ ex) * 8);
#pragma unroll
        for (int n4 = 0; n4 < 4; ++n4) {
            const unsigned short* brow =
                Wt + (size_t)(wid * 64 + n4 * 16 + lr) * K + kk * 32 + lk * 8;
            bf16x8 bv = *(const bf16x8*)brow;
            acc[n4] = __builtin_amdgcn_mfma_f32_16x16x32_bf16(av, bv, acc[n4], 0, 0, 0);
        }
    }

    if (lk < 2) {
#pragma unroll
        for (int n4 = 0; n4 < 4; ++n4) {
            int col = wid * 64 + n4 * 16 + lr;
            float bb = bias[col];
#pragma unroll
            for (int rr = 0; rr < 4; ++rr) {
                int node = blockIdx.x * 8 + (lk << 2) + rr;
                unsigned short v = f2bf(fmaxf(acc[n4][rr] + bb, 0.f));
                size_t idx = (size_t)node * N_UNITS + col;
                x_out[idx] = v;
                unsigned short jm = jk[idx];
                jk[idx] = (v > jm) ? v : jm;  // non-negative bf16: bit cmp == val cmp
            }
        }
    }
}

// ---------------- z-gather: z = dinv[n]*sum(dinv[src]*jk[src]) + invdeg[n]*jk[n] ----------------

__global__ __launch_bounds__(256) void k_zg(const unsigned short* __restrict__ jk,
                                            const int* __restrict__ row_ptr,
                                            const int* __restrict__ csr_src,
                                            const float* __restrict__ dinv,
                                            const float* __restrict__ invdeg,
                                            unsigned short* __restrict__ z) {
    const int tg = threadIdx.x >> 5, sl = threadIdx.x & 31;
    const int n = blockIdx.x * 8 + tg;
    const int s = row_ptr[n], e = row_ptr[n + 1];
    const uint4* jv = (const uint4*)jk;

    float a[8];
#pragma unroll
    for (int j = 0; j < 8; ++j) a[j] = 0.f;

#define ACCW(u, d)                                                     \
    do {                                                               \
        a[0] += bf2f((u).x) * (d); a[1] += bf2f((u).x >> 16) * (d);    \
        a[2] += bf2f((u).y) * (d); a[3] += bf2f((u).y >> 16) * (d);    \
        a[4] += bf2f((u).z) * (d); a[5] += bf2f((u).z >> 16) * (d);    \
        a[6] += bf2f((u).w) * (d); a[7] += bf2f((u).w >> 16) * (d);    \
    } while (0)

    int i = s;
    for (; i + 1 < e; i += 2) {
        int s0 = csr_src[i], s1 = csr_src[i + 1];
        uint4 u0 = jv[(size_t)s0 * 32 + sl];
        uint4 u1 = jv[(size_t)s1 * 32 + sl];
        float d0 = dinv[s0], d1 = dinv[s1];
        ACCW(u0, d0); ACCW(u1, d1);
    }
    for (; i < e; ++i) {
        int sr = csr_src[i];
        uint4 u = jv[(size_t)sr * 32 + sl];
        float d = dinv[sr];
        ACCW(u, d);
    }
#undef ACCW

    float dn = dinv[n], idg = invdeg[n];
    uint4 un = jv[(size_t)n * 32 + sl];
    uint4 o;
    o.x = f2bf(dn * a[0] + idg * bf2f(un.x)) |
          ((unsigned)f2bf(dn * a[1] + idg * bf2f(un.x >> 16)) << 16);
    o.y = f2bf(dn * a[2] + idg * bf2f(un.y)) |
          ((unsigned)f2bf(dn * a[3] + idg * bf2f(un.y >> 16)) << 16);
    o.z = f2bf(dn * a[4] + idg * bf2f(un.z)) |
          ((unsigned)f2bf(dn * a[5] + idg * bf2f(un.z >> 16)) << 16);
    o.w = f2bf(dn * a[6] + idg * bf2f(un.w)) |
          ((unsigned)f2bf(dn * a[7] + idg * bf2f(un.w >> 16)) << 16);
    ((uint4*)z)[(size_t)n * 32 + sl] = o;
}

// ---------------- final GEMM + bias + log_softmax: out = lsm(z@Wot^T + bo) ----------------
// 157 blocks x 64 rows; K=256, 64 out cols; k_wgemm tile mapping (proven) + softmax epilogue.

__global__ __launch_bounds__(256) void k_fg(const unsigned short* __restrict__ z,
                                            const unsigned short* __restrict__ Wot,
                                            const float* __restrict__ bo,
                                            float* __restrict__ out) {
    constexpr int K = 256;
    __shared__ unsigned short As[64 * K];
    __shared__ unsigned short Bs[64 * K];

    const int tid  = threadIdx.x;
    const int wid  = tid >> 6;
    const int lane = tid & 63;
    const int lr   = lane & 15;
    const int lk   = lane >> 4;
    const int brow = blockIdx.x * 64;

#pragma unroll
    for (int p = 0; p < 8; ++p) {
        int i = p * 256 + tid;
        int row = i >> 5, s = i & 31;
        int gr = brow + row; if (gr >= N_NODES) gr = N_NODES - 1;
        const unsigned short* gp = z + (size_t)gr * K + ((s ^ (row & 7)) * 8);
        __builtin_amdgcn_global_load_lds(
            (const __attribute__((address_space(1))) void*)gp,
            (__attribute__((address_space(3))) void*)(As + i * 8), 16, 0, 0);
    }
#pragma unroll
    for (int p = 0; p < 8; ++p) {
        int i = p * 256 + tid;
        int row = i >> 5, s = i & 31;
        const unsigned short* gp = Wot + (size_t)row * K + ((s ^ (row & 7)) * 8);
        __builtin_amdgcn_global_load_lds(
            (const __attribute__((address_space(1))) void*)gp,
            (__attribute__((address_space(3))) void*)(Bs + i * 8), 16, 0, 0);
    }
    __syncthreads();

    f32x4 acc[4];
#pragma unroll
    for (int n4 = 0; n4 < 4; ++n4) acc[n4] = (f32x4){0.f, 0.f, 0.f, 0.f};

    const unsigned short* Arow = As + ((wid << 4) + lr) * K;
    const int ex = lr & 7;
#pragma unroll
    for (int kk = 0; kk < 8; ++kk) {
        bf16x8 av = *(const bf16x8*)(&Arow[(((kk << 2) + lk) ^ ex) * 8]);
#pragma unroll
        for (int n4 = 0; n4 < 4; ++n4) {
            const unsigned short* Brow = Bs + ((n4 << 4) + lr) * K;
            bf16x8 bv = *(const bf16x8*)(&Brow[(((kk << 2) + lk) ^ ex) * 8]);
            acc[n4] = __builtin_amdgcn_mfma_f32_16x16x32_bf16(av, bv, acc[n4], 0, 0, 0);
        }
    }

    float bb[4];
#pragma unroll
    for (int n4 = 0; n4 < 4; ++n4) bb[n4] = bo[n4 * 16 + lr];

#pragma unroll
    for (int rr = 0; rr < 4; ++rr) {
        float v0 = acc[0][rr] + bb[0];
        float v1 = acc[1][rr] + bb[1];
        float v2 = acc[2][rr] + bb[2];
        float v3 = acc[3][rr] + bb[3];
        float mx = fmaxf(fmaxf(v0, v1), fmaxf(v2, v3));
#pragma unroll
        for (int off = 8; off; off >>= 1) mx = fmaxf(mx, __shfl_xor(mx, off));
        float sm = __expf(v0 - mx) + __expf(v1 - mx) + __expf(v2 - mx) + __expf(v3 - mx);
#pragma unroll
        for (int off = 8; off; off >>= 1) sm += __shfl_xor(sm, off);
        float ls = mx + __logf(sm);
        int orow = brow + (wid << 4) + (lk << 2) + rr;
        if (orow < N_NODES) {
            out[(size_t)orow * OUT_FEATS + 0 * 16 + lr] = v0 - ls;
            out[(size_t)orow * OUT_FEATS + 1 * 16 + lr] = v1 - ls;
            out[(size_t)orow * OUT_FEATS + 2 * 16 + lr] = v2 - ls;
            out[(size_t)orow * OUT_FEATS + 3 * 16 + lr] = v3 - ls;
        }
    }
}

// ---------------- launch ----------------

extern "C" void kernel_launch(void* const* d_in, const int* in_sizes, int n_in,
                              void* d_out, int out_size, void* d_ws, size_t ws_size,
                              hipStream_t stream) {
    const float* h  = (const float*)d_in[0];
    const int*   ei = (const int*)d_in[1];
    const float* W0 = (const float*)d_in[2];
    const float* b0 = (const float*)d_in[3];
    const float* Wh = (const float*)d_in[4];
    const float* bh = (const float*)d_in[5];
    const float* Wo = (const float*)d_in[6];
    const float* bo = (const float*)d_in[7];

    const int* src = ei;
    const int* dst = ei + N_EDGES;

    char* p = (char*)d_ws;
    auto carve = [&](size_t bytes) {
        char* r = p;
        p += (bytes + 255) & ~(size_t)255;
        return r;
    };
    int*   deg     = (int*)  carve(N_NODES * 4);
    int*   row_ptr = (int*)  carve((N_NODES + 1) * 4);
    int*   cursor  = (int*)  carve(N_NODES * 4);
    int*   csr_src = (int*)  carve(N_EDGES * 4);
    float* dinv    = (float*)carve(N_NODES * 4);
    float* invdeg  = (float*)carve(N_NODES * 4);
    unsigned short* hb  = (unsigned short*)carve((size_t)N_NODES * IN_FEATS * 2);
    unsigned short* W0t = (unsigned short*)carve((size_t)IN_FEATS * N_UNITS * 2);
    unsigned short* Wht = (unsigned short*)carve((size_t)N_HID * N_UNITS * N_UNITS * 2);
    unsigned short* Wot = (unsigned short*)carve((size_t)N_UNITS * OUT_FEATS * 2);
    unsigned short* xa  = (unsigned short*)carve((size_t)N_NODES * N_UNITS * 2);
    unsigned short* xb  = (unsigned short*)carve((size_t)N_NODES * N_UNITS * 2);
    unsigned short* jk  = (unsigned short*)carve((size_t)N_NODES * N_UNITS * 2);
    unsigned short* z   = (unsigned short*)carve((size_t)N_NODES * N_UNITS * 2);

    hipMemsetAsync(deg, 0, N_NODES * 4, stream);
    {
        const int total = N_EDGES + N_NODES * IN_FEATS / 4 +
                          IN_FEATS * N_UNITS + N_HID * N_UNITS * N_UNITS + N_UNITS * OUT_FEATS;
        k_setup<<<(total + 255) / 256, 256, 0, stream>>>(dst, deg, h, hb, W0, Wh, Wo,
                                                         W0t, Wht, Wot);
    }
    k_scan<<<1, 1024, 0, stream>>>(deg, row_ptr, cursor, dinv, invdeg);
    k_fill<<<(N_EDGES + 255) / 256, 256, 0, stream>>>(src, dst, cursor, csr_src);

    // layer 0 fused: x1 = relu(agg(h)@W0 + b0), jk init
    k_l0<<<N_NODES / 8, 256, 0, stream>>>(hb, row_ptr, csr_src, W0t, b0, xa, jk);

    // hidden layers fused, ping-pong
    unsigned short* cur = xa;
    unsigned short* nxt = xb;
    for (int l = 0; l < N_HID; ++l) {
        k_lh<<<N_NODES / 8, 256, 0, stream>>>(cur, row_ptr, csr_src,
                                              Wht + (size_t)l * N_UNITS * N_UNITS,
                                              bh + (size_t)l * N_UNITS, nxt, jk);
        unsigned short* t = cur; cur = nxt; nxt = t;
    }

    // final: z-gather then GEMM + bias + log_softmax
    k_zg<<<N_NODES / 8, 256, 0, stream>>>(jk, row_ptr, csr_src, dinv, invdeg, z);
    k_fg<<<(N_NODES + 63) / 64, 256, 0, stream>>>(z, Wot, bo, (float*)d_out);
}

// Round 10
// 270.452 us; speedup vs baseline: 5.1659x; 1.2823x over previous
//
#include <hip/hip_runtime.h>
#include <math.h>

#define N_NODES 10000
#define N_EDGES 320000
#define IN_FEATS 512
#define N_UNITS 256
#define OUT_FEATS 64
#define N_HID 5  // hidden Wh layers

typedef __attribute__((ext_vector_type(8))) short bf16x8;
typedef __attribute__((ext_vector_type(4))) float f32x4;

__device__ __forceinline__ unsigned short f2bf(float f) {
    union { float f; unsigned int u; } c; c.f = f;
    unsigned int u = c.u + 0x7FFFu + ((c.u >> 16) & 1u);  // RNE
    return (unsigned short)(u >> 16);
}
__device__ __forceinline__ float bf2f(unsigned int b) {
    union { unsigned int u; float f; } c; c.u = (b & 0xffffu) << 16;
    return c.f;
}

// ---------------- fused setup: deg histogram + h->bf16 + weights->bf16 transposed ----------------

__global__ void k_setup(const int* __restrict__ dst, int* __restrict__ deg,
                        const float* __restrict__ h, unsigned short* __restrict__ hb,
                        const float* __restrict__ W0, const float* __restrict__ Wh,
                        const float* __restrict__ Wo,
                        unsigned short* __restrict__ W0t, unsigned short* __restrict__ Wht,
                        unsigned short* __restrict__ Wot) {
    const int R1 = N_EDGES;
    const int R2 = N_NODES * IN_FEATS / 4;
    const int S0 = IN_FEATS * N_UNITS;
    const int SH = N_HID * N_UNITS * N_UNITS;
    const int SO = N_UNITS * OUT_FEATS;
    int t = blockIdx.x * blockDim.x + threadIdx.x;
    if (t < R1) {
        atomicAdd(&deg[dst[t]], 1);
    } else if (t < R1 + R2) {
        int u = t - R1;
        float4 v = reinterpret_cast<const float4*>(h)[u];
        ushort4 o;
        o.x = f2bf(v.x); o.y = f2bf(v.y); o.z = f2bf(v.z); o.w = f2bf(v.w);
        reinterpret_cast<ushort4*>(hb)[u] = o;
    } else {
        int u = t - R1 - R2;
        if (u < S0) {
            int k = u >> 8, n = u & 255;
            W0t[(size_t)n * IN_FEATS + k] = f2bf(W0[u]);
        } else if (u < S0 + SH) {
            int w = u - S0;
            int l = w >> 16, r = w & 65535;
            int k = r >> 8, n = r & 255;
            Wht[(size_t)l * 65536 + (size_t)n * N_UNITS + k] = f2bf(Wh[w]);
        } else if (u < S0 + SH + SO) {
            int w = u - S0 - SH;
            int k = w >> 6, n = w & 63;
            Wot[(size_t)n * N_UNITS + k] = f2bf(Wo[w]);
        }
    }
}

// ---------------- scan: one 1024-thread block, 10/thread, 3 barriers ----------------

__global__ __launch_bounds__(1024) void k_scan(const int* __restrict__ deg,
                                               int* __restrict__ row_ptr,
                                               int* __restrict__ cursor,
                                               float* __restrict__ dinv,
                                               float* __restrict__ invdeg) {
    __shared__ int wsum[16];
    const int PER = 10;
    int t = threadIdx.x;
    int lane = t & 63, wid = t >> 6;
    int base = t * PER;

    int v[PER];
    int s = 0;
#pragma unroll
    for (int j = 0; j < PER; ++j) {
        int i = base + j;
        int d = (i < N_NODES) ? deg[i] : 0;
        v[j] = s;
        s += d;
    }
    int inc = s;
#pragma unroll
    for (int off = 1; off < 64; off <<= 1) {
        int y = __shfl_up(inc, off);
        if (lane >= off) inc += y;
    }
    if (lane == 63) wsum[wid] = inc;
    __syncthreads();
    if (wid == 0) {
        int w = (lane < 16) ? wsum[lane] : 0;
#pragma unroll
        for (int off = 1; off < 16; off <<= 1) {
            int y = __shfl_up(w, off);
            if (lane >= off) w += y;
        }
        if (lane < 16) wsum[lane] = w;
    }
    __syncthreads();
    int wave_excl = (wid == 0) ? 0 : wsum[wid - 1];
    int thread_excl = wave_excl + (inc - s);

#pragma unroll
    for (int j = 0; j < PER; ++j) {
        int i = base + j;
        if (i < N_NODES) {
            int rp = thread_excl + v[j];
            row_ptr[i] = rp;
            cursor[i]  = rp;
            int d = ((j + 1 < PER) ? v[j + 1] : s) - v[j];
            float dd = (float)(d + 1);
            dinv[i]   = rsqrtf(dd);
            invdeg[i] = 1.0f / dd;
        }
    }
    if (t == 1023) row_ptr[N_NODES] = thread_excl + s;
}

__global__ void k_fill(const int* __restrict__ src, const int* __restrict__ dst,
                       int* __restrict__ cursor, int* __restrict__ csr_src) {
    int e = blockIdx.x * blockDim.x + threadIdx.x;
    if (e < N_EDGES) {
        int p = atomicAdd(&cursor[dst[e]], 1);
        csr_src[p] = src[e];
    }
}

// ---------------- layer-0 GEMM (K=512): 64x64 tile, BK=32, 2-phase dbuf, swizzled LDS ----------------

__global__ __launch_bounds__(256) void k_mgemm(const unsigned short* __restrict__ A,
                                               const unsigned short* __restrict__ Bt,
                                               unsigned short* __restrict__ C,
                                               const int M, const int K, const int Nld) {
    constexpr int BM = 64, BN = 64, BK = 32;
    __shared__ unsigned short As[2][BM * BK];
    __shared__ unsigned short Bs[2][BN * BK];

    const int tid  = threadIdx.x;
    const int wid  = tid >> 6;
    const int lane = tid & 63;
    const int wr   = wid >> 1;
    const int wc   = wid & 1;
    const int brow = blockIdx.y * BM;
    const int bcol = blockIdx.x * BN;

    const int lr = lane & 15;
    const int lk = lane >> 4;

    const int row  = tid >> 2;
    const int slot = tid & 3;
    const int sslot = slot ^ ((row >> 1) & 3);

    int gra = brow + row; if (gra >= M) gra = M - 1;
    const unsigned short* gpa = A + (size_t)gra * K + sslot * 8;
    const unsigned short* gpb = Bt + (size_t)(bcol + row) * K + sslot * 8;

    f32x4 acc[2][2];
#pragma unroll
    for (int m = 0; m < 2; ++m)
#pragma unroll
        for (int n = 0; n < 2; ++n)
            acc[m][n] = (f32x4){0.f, 0.f, 0.f, 0.f};

#define STAGE(buf, k0)                                                                      \
    do {                                                                                    \
        __builtin_amdgcn_global_load_lds(                                                   \
            (const __attribute__((address_space(1))) void*)(gpa + (k0)),                    \
            (__attribute__((address_space(3))) void*)(&As[(buf)][tid * 8]), 16, 0, 0);      \
        __builtin_amdgcn_global_load_lds(                                                   \
            (const __attribute__((address_space(1))) void*)(gpb + (k0)),                    \
            (__attribute__((address_space(3))) void*)(&Bs[(buf)][tid * 8]), 16, 0, 0);      \
    } while (0)

    STAGE(0, 0);
    __syncthreads();

    const int nk = K / BK;
    for (int kt = 0; kt < nk; ++kt) {
        const int cur = kt & 1;
        if (kt + 1 < nk) STAGE(cur ^ 1, (kt + 1) * BK);

        bf16x8 af[2], bfr[2];
#pragma unroll
        for (int m = 0; m < 2; ++m) {
            int ra = wr * 32 + m * 16 + lr;
            af[m] = *reinterpret_cast<const bf16x8*>(&As[cur][ra * BK + (lk ^ ((ra >> 1) & 3)) * 8]);
        }
#pragma unroll
        for (int n = 0; n < 2; ++n) {
            int rb = wc * 32 + n * 16 + lr;
            bfr[n] = *reinterpret_cast<const bf16x8*>(&Bs[cur][rb * BK + (lk ^ ((rb >> 1) & 3)) * 8]);
        }
#pragma unroll
        for (int m = 0; m < 2; ++m)
#pragma unroll
            for (int n = 0; n < 2; ++n)
                acc[m][n] = __builtin_amdgcn_mfma_f32_16x16x32_bf16(af[m], bfr[n], acc[m][n], 0, 0, 0);
        __syncthreads();
    }
#undef STAGE

#pragma unroll
    for (int m = 0; m < 2; ++m) {
#pragma unroll
        for (int r = 0; r < 4; ++r) {
            int orow = brow + wr * 32 + m * 16 + lk * 4 + r;
            if (orow < M) {
#pragma unroll
                for (int n = 0; n < 2; ++n) {
                    int ocol = bcol + wc * 32 + n * 16 + lr;
                    C[(size_t)orow * Nld + ocol] = f2bf(acc[m][n][r]);
                }
            }
        }
    }
}

// ---------------- agg layer 0: CSR agg + bias + relu, writes x + jk (halfsel L2 split) ----------------

__global__ __launch_bounds__(256) void k_agg0(const unsigned short* __restrict__ m,
                                              const int* __restrict__ row_ptr,
                                              const int* __restrict__ csr_src,
                                              const float* __restrict__ bias,
                                              unsigned short* __restrict__ x_out,
                                              unsigned short* __restrict__ jk) {
    const int halfsel = (blockIdx.x >= 625) ? 1 : 0;
    const int g = blockIdx.x - halfsel * 625;
    const int nib  = threadIdx.x >> 4;
    const int lane = threadIdx.x & 15;
    const int n = g * 16 + nib;
    const int s = row_ptr[n], e = row_ptr[n + 1];
    const uint4* mv = (const uint4*)m;
    const int off = halfsel * 16 + lane;

    float a[8];
#pragma unroll
    for (int j = 0; j < 8; ++j) a[j] = 0.f;

#define ACC8(u)                                        \
    do {                                               \
        a[0] += bf2f((u).x); a[1] += bf2f((u).x >> 16);\
        a[2] += bf2f((u).y); a[3] += bf2f((u).y >> 16);\
        a[4] += bf2f((u).z); a[5] += bf2f((u).z >> 16);\
        a[6] += bf2f((u).w); a[7] += bf2f((u).w >> 16);\
    } while (0)

    int i = s;
    for (; i + 3 < e; i += 4) {
        int s0 = csr_src[i], s1 = csr_src[i + 1], s2 = csr_src[i + 2], s3 = csr_src[i + 3];
        uint4 u0 = mv[(size_t)s0 * 32 + off];
        uint4 u1 = mv[(size_t)s1 * 32 + off];
        uint4 u2 = mv[(size_t)s2 * 32 + off];
        uint4 u3 = mv[(size_t)s3 * 32 + off];
        ACC8(u0); ACC8(u1); ACC8(u2); ACC8(u3);
    }
    for (; i < e; ++i) {
        uint4 u = mv[(size_t)csr_src[i] * 32 + off];
        ACC8(u);
    }
#undef ACC8

    float4 b0 = ((const float4*)bias)[halfsel * 32 + lane * 2];
    float4 b1 = ((const float4*)bias)[halfsel * 32 + lane * 2 + 1];
    unsigned int hh[8];
    hh[0] = f2bf(fmaxf(a[0] + b0.x, 0.f));
    hh[1] = f2bf(fmaxf(a[1] + b0.y, 0.f));
    hh[2] = f2bf(fmaxf(a[2] + b0.z, 0.f));
    hh[3] = f2bf(fmaxf(a[3] + b0.w, 0.f));
    hh[4] = f2bf(fmaxf(a[4] + b1.x, 0.f));
    hh[5] = f2bf(fmaxf(a[5] + b1.y, 0.f));
    hh[6] = f2bf(fmaxf(a[6] + b1.z, 0.f));
    hh[7] = f2bf(fmaxf(a[7] + b1.w, 0.f));
    uint4 o;
    o.x = hh[0] | (hh[1] << 16);
    o.y = hh[2] | (hh[3] << 16);
    o.z = hh[4] | (hh[5] << 16);
    o.w = hh[6] | (hh[7] << 16);

    size_t idx = (size_t)n * 32 + off;
    ((uint4*)x_out)[idx] = o;
    ((uint4*)jk)[idx] = o;
}

// ---------------- fused hidden layer: x_out = relu(agg(x_in)@W^T + b), jk = max ----------------
// 16 nodes/block (625 blocks). Gather u = agg(x_in) into LDS (16 rows, all real),
// then u @ Wt^T with W staged through LDS in four 64-col tiles (global_load_lds, XOR swizzle).

__global__ __launch_bounds__(256) void k_lh16(const unsigned short* __restrict__ x_in,
                                              const int* __restrict__ row_ptr,
                                              const int* __restrict__ csr_src,
                                              const unsigned short* __restrict__ Wt,
                                              const float* __restrict__ bias,
                                              unsigned short* __restrict__ x_out,
                                              unsigned short* __restrict__ jk) {
    constexpr int K = N_UNITS;  // 256
    __shared__ unsigned short U[16 * K];    // 8 KB
    __shared__ unsigned short Bs[64 * K];   // 32 KB

    const int tid = threadIdx.x;
    const int r = tid >> 4, sl = tid & 15;   // node-in-block, lane
    const int n = blockIdx.x * 16 + r;
    const int s = row_ptr[n], e = row_ptr[n + 1];
    const uint4* xv = (const uint4*)x_in;    // 32 uint4 per row

    float a[16];
#pragma unroll
    for (int j = 0; j < 16; ++j) a[j] = 0.f;

#define ACCL(u, base)                                                        \
    do {                                                                     \
        a[base + 0] += bf2f((u).x); a[base + 1] += bf2f((u).x >> 16);        \
        a[base + 2] += bf2f((u).y); a[base + 3] += bf2f((u).y >> 16);        \
        a[base + 4] += bf2f((u).z); a[base + 5] += bf2f((u).z >> 16);        \
        a[base + 6] += bf2f((u).w); a[base + 7] += bf2f((u).w >> 16);        \
    } while (0)

    int i = s;
    for (; i + 1 < e; i += 2) {
        int s0 = csr_src[i], s1 = csr_src[i + 1];
        uint4 u0 = xv[(size_t)s0 * 32 + sl];
        uint4 u1 = xv[(size_t)s0 * 32 + 16 + sl];
        uint4 u2 = xv[(size_t)s1 * 32 + sl];
        uint4 u3 = xv[(size_t)s1 * 32 + 16 + sl];
        ACCL(u0, 0); ACCL(u1, 8); ACCL(u2, 0); ACCL(u3, 8);
    }
    for (; i < e; ++i) {
        int sr = csr_src[i];
        uint4 u0 = xv[(size_t)sr * 32 + sl];
        uint4 u1 = xv[(size_t)sr * 32 + 16 + sl];
        ACCL(u0, 0); ACCL(u1, 8);
    }
#undef ACCL

    uint4 o0, o1;
    o0.x = f2bf(a[0])  | ((unsigned)f2bf(a[1])  << 16);
    o0.y = f2bf(a[2])  | ((unsigned)f2bf(a[3])  << 16);
    o0.z = f2bf(a[4])  | ((unsigned)f2bf(a[5])  << 16);
    o0.w = f2bf(a[6])  | ((unsigned)f2bf(a[7])  << 16);
    o1.x = f2bf(a[8])  | ((unsigned)f2bf(a[9])  << 16);
    o1.y = f2bf(a[10]) | ((unsigned)f2bf(a[11]) << 16);
    o1.z = f2bf(a[12]) | ((unsigned)f2bf(a[13]) << 16);
    o1.w = f2bf(a[14]) | ((unsigned)f2bf(a[15]) << 16);
    // row r, logical slots sl and sl+16; physical slot = logical ^ (r&7)
    ((uint4*)U)[r * 32 + (sl ^ (r & 7))] = o0;
    ((uint4*)U)[r * 32 + ((sl + 16) ^ (r & 7))] = o1;
    __syncthreads();

    const int wid = tid >> 6, lane = tid & 63;
    const int lr = lane & 15, lk = lane >> 4;
    const unsigned short* Urow = U + lr * K;
    const int ex = lr & 7;

    for (int ct = 0; ct < 4; ++ct) {
        // stage Wt rows [ct*64, +64) -> Bs, src-XOR swizzled, LDS linear (rule 21)
#pragma unroll
        for (int p = 0; p < 8; ++p) {
            int i2 = p * 256 + tid;
            int row = i2 >> 5, sx = i2 & 31;
            const unsigned short* gp = Wt + (size_t)(ct * 64 + row) * K + ((sx ^ (row & 7)) * 8);
            __builtin_amdgcn_global_load_lds(
                (const __attribute__((address_space(1))) void*)gp,
                (__attribute__((address_space(3))) void*)(Bs + i2 * 8), 16, 0, 0);
        }
        __syncthreads();

        f32x4 acc = (f32x4){0.f, 0.f, 0.f, 0.f};
        const unsigned short* Brow = Bs + (wid * 16 + lr) * K;
#pragma unroll
        for (int kk = 0; kk < 8; ++kk) {
            bf16x8 av = *(const bf16x8*)(Urow + (((kk << 2) + lk) ^ ex) * 8);
            bf16x8 bv = *(const bf16x8*)(Brow + (((kk << 2) + lk) ^ ex) * 8);
            acc = __builtin_amdgcn_mfma_f32_16x16x32_bf16(av, bv, acc, 0, 0, 0);
        }

        // epilogue: wave wid covers cols [ct*64 + wid*16, +16); rows = 16 nodes
        int col = ct * 64 + wid * 16 + lr;
        float bb = bias[col];
#pragma unroll
        for (int rr = 0; rr < 4; ++rr) {
            int node = blockIdx.x * 16 + (lk << 2) + rr;
            unsigned short v = f2bf(fmaxf(acc[rr] + bb, 0.f));
            size_t idx = (size_t)node * N_UNITS + col;
            x_out[idx] = v;
            unsigned short jm = jk[idx];
            jk[idx] = (v > jm) ? v : jm;  // non-negative bf16: bit cmp == val cmp
        }
        __syncthreads();  // Bs reads done before next stage overwrite
    }
}

// ---------------- final weight GEMM (K=256, 64 out cols): mf = jk @ Wot^T ----------------

__global__ __launch_bounds__(256) void k_wgemm(const unsigned short* __restrict__ A,
                                               const unsigned short* __restrict__ Bt,
                                               unsigned short* __restrict__ C,
                                               const int M, const int Nld) {
    constexpr int K = 256;
    __shared__ unsigned short As[64 * K];
    __shared__ unsigned short Bs[64 * K];

    const int tid  = threadIdx.x;
    const int wid  = tid >> 6;
    const int lane = tid & 63;
    const int lr   = lane & 15;
    const int lk   = lane >> 4;
    const int brow = blockIdx.x * 64;
    const int bcol = 0;

#pragma unroll
    for (int p = 0; p < 8; ++p) {
        int i = p * 256 + tid;
        int row = i >> 5, s = i & 31;
        int gr = brow + row; if (gr >= M) gr = M - 1;
        const unsigned short* gp = A + (size_t)gr * K + ((s ^ (row & 7)) * 8);
        __builtin_amdgcn_global_load_lds(
            (const __attribute__((address_space(1))) void*)gp,
            (__attribute__((address_space(3))) void*)(As + i * 8), 16, 0, 0);
    }
#pragma unroll
    for (int p = 0; p < 8; ++p) {
        int i = p * 256 + tid;
        int row = i >> 5, s = i & 31;
        const unsigned short* gp = Bt + (size_t)(bcol + row) * K + ((s ^ (row & 7)) * 8);
        __builtin_amdgcn_global_load_lds(
            (const __attribute__((address_space(1))) void*)gp,
            (__attribute__((address_space(3))) void*)(Bs + i * 8), 16, 0, 0);
    }
    __syncthreads();

    f32x4 acc[4];
#pragma unroll
    for (int n = 0; n < 4; ++n) acc[n] = (f32x4){0.f, 0.f, 0.f, 0.f};

    const int ra = (wid << 4) + lr;
    const unsigned short* Arow = As + ra * K;
    const int e = lr & 7;
#pragma unroll
    for (int kk = 0; kk < 8; ++kk) {
        bf16x8 av = *reinterpret_cast<const bf16x8*>(&Arow[(((kk << 2) + lk) ^ e) * 8]);
#pragma unroll
        for (int n = 0; n < 4; ++n) {
            const unsigned short* Brow = Bs + ((n << 4) + lr) * K;
            bf16x8 bv = *reinterpret_cast<const bf16x8*>(&Brow[(((kk << 2) + lk) ^ e) * 8]);
            acc[n] = __builtin_amdgcn_mfma_f32_16x16x32_bf16(av, bv, acc[n], 0, 0, 0);
        }
    }

#pragma unroll
    for (int n = 0; n < 4; ++n) {
#pragma unroll
        for (int r = 0; r < 4; ++r) {
            int orow = brow + (wid << 4) + (lk << 2) + r;
            if (orow < M) {
                int ocol = bcol + (n << 4) + lr;
                C[(size_t)orow * Nld + ocol] = f2bf(acc[n][r]);
            }
        }
    }
}

// ---------------- final GCN-norm agg + self loop + bias + log_softmax ----------------

__global__ __launch_bounds__(256) void k_final(const unsigned short* __restrict__ mf,
                                               const int* __restrict__ row_ptr,
                                               const int* __restrict__ csr_src,
                                               const float* __restrict__ dinv,
                                               const float* __restrict__ invdeg,
                                               const float* __restrict__ bo,
                                               float* __restrict__ out) {
    int halfw = threadIdx.x >> 5;
    int wl = threadIdx.x & 31;
    const unsigned int* mfu = (const unsigned int*)mf;
    int n = blockIdx.x * 8 + halfw;
    int s = row_ptr[n], e = row_ptr[n + 1];

    float a0 = 0.f, a1 = 0.f;
    int i = s;
    for (; i + 1 < e; i += 2) {
        int s0 = csr_src[i], s1 = csr_src[i + 1];
        unsigned int u0 = mfu[(size_t)s0 * 32 + wl];
        unsigned int u1 = mfu[(size_t)s1 * 32 + wl];
        float d0 = dinv[s0], d1 = dinv[s1];
        a0 += bf2f(u0) * d0 + bf2f(u1) * d1;
        a1 += bf2f(u0 >> 16) * d0 + bf2f(u1 >> 16) * d1;
    }
    for (; i < e; ++i) {
        int sr = csr_src[i];
        unsigned int u = mfu[(size_t)sr * 32 + wl];
        float dv = dinv[sr];
        a0 += bf2f(u) * dv;
        a1 += bf2f(u >> 16) * dv;
    }
    float dn = dinv[n];
    a0 *= dn; a1 *= dn;
    unsigned int un = mfu[(size_t)n * 32 + wl];
    float idg = invdeg[n];
    float2 bo2 = ((const float2*)bo)[wl];
    a0 += bf2f(un) * idg + bo2.x;
    a1 += bf2f(un >> 16) * idg + bo2.y;

    float mx = fmaxf(a0, a1);
#pragma unroll
    for (int off = 16; off; off >>= 1) mx = fmaxf(mx, __shfl_xor(mx, off));
    float e0 = __expf(a0 - mx), e1 = __expf(a1 - mx);
    float sum = e0 + e1;
#pragma unroll
    for (int off = 16; off; off >>= 1) sum += __shfl_xor(sum, off);
    float ls = __logf(sum);
    float2 r;
    r.x = a0 - mx - ls;
    r.y = a1 - mx - ls;
    ((float2*)out)[(size_t)n * 32 + wl] = r;
}

// ---------------- launch ----------------

extern "C" void kernel_launch(void* const* d_in, const int* in_sizes, int n_in,
                              void* d_out, int out_size, void* d_ws, size_t ws_size,
                              hipStream_t stream) {
    const float* h  = (const float*)d_in[0];
    const int*   ei = (const int*)d_in[1];
    const float* W0 = (const float*)d_in[2];
    const float* b0 = (const float*)d_in[3];
    const float* Wh = (const float*)d_in[4];
    const float* bh = (const float*)d_in[5];
    const float* Wo = (const float*)d_in[6];
    const float* bo = (const float*)d_in[7];

    const int* src = ei;
    const int* dst = ei + N_EDGES;

    char* p = (char*)d_ws;
    auto carve = [&](size_t bytes) {
        char* r = p;
        p += (bytes + 255) & ~(size_t)255;
        return r;
    };
    int*   deg     = (int*)  carve(N_NODES * 4);
    int*   row_ptr = (int*)  carve((N_NODES + 1) * 4);
    int*   cursor  = (int*)  carve(N_NODES * 4);
    int*   csr_src = (int*)  carve(N_EDGES * 4);
    float* dinv    = (float*)carve(N_NODES * 4);
    float* invdeg  = (float*)carve(N_NODES * 4);
    unsigned short* hb  = (unsigned short*)carve((size_t)N_NODES * IN_FEATS * 2);
    unsigned short* W0t = (unsigned short*)carve((size_t)IN_FEATS * N_UNITS * 2);
    unsigned short* Wht = (unsigned short*)carve((size_t)N_HID * N_UNITS * N_UNITS * 2);
    unsigned short* Wot = (unsigned short*)carve((size_t)N_UNITS * OUT_FEATS * 2);
    unsigned short* m   = (unsigned short*)carve((size_t)N_NODES * N_UNITS * 2);
    unsigned short* xa  = (unsigned short*)carve((size_t)N_NODES * N_UNITS * 2);
    unsigned short* xb  = (unsigned short*)carve((size_t)N_NODES * N_UNITS * 2);
    unsigned short* jk  = (unsigned short*)carve((size_t)N_NODES * N_UNITS * 2);
    unsigned short* mf  = (unsigned short*)carve((size_t)N_NODES * OUT_FEATS * 2);

    hipMemsetAsync(deg, 0, N_NODES * 4, stream);
    {
        const int total = N_EDGES + N_NODES * IN_FEATS / 4 +
                          IN_FEATS * N_UNITS + N_HID * N_UNITS * N_UNITS + N_UNITS * OUT_FEATS;
        k_setup<<<(total + 255) / 256, 256, 0, stream>>>(dst, deg, h, hb, W0, Wh, Wo,
                                                         W0t, Wht, Wot);
    }
    k_scan<<<1, 1024, 0, stream>>>(deg, row_ptr, cursor, dinv, invdeg);
    k_fill<<<(N_EDGES + 255) / 256, 256, 0, stream>>>(src, dst, cursor, csr_src);

    const int GBM = (N_NODES + 63) / 64;  // 157

    // layer 0: m = hb @ W0t^T (K=512) then agg+bias+relu -> xa, jk init
    {
        dim3 g(N_UNITS / 64, GBM);
        k_mgemm<<<g, 256, 0, stream>>>(hb, W0t, m, N_NODES, IN_FEATS, N_UNITS);
    }
    k_agg0<<<1250, 256, 0, stream>>>(m, row_ptr, csr_src, b0, xa, jk);

    // hidden layers: fused agg-first (agg(x)@W), ping-pong
    unsigned short* cur = xa;
    unsigned short* nxt = xb;
    for (int l = 0; l < N_HID; ++l) {
        k_lh16<<<625, 256, 0, stream>>>(cur, row_ptr, csr_src,
                                        Wht + (size_t)l * N_UNITS * N_UNITS,
                                        bh + (size_t)l * N_UNITS, nxt, jk);
        unsigned short* t = cur; cur = nxt; nxt = t;
    }

    // final: mf = jk @ Wot^T then GCN-norm + log_softmax
    k_wgemm<<<GBM, 256, 0, stream>>>(jk, Wot, mf, N_NODES, OUT_FEATS);
    k_final<<<N_NODES / 8, 256, 0, stream>>>(mf, row_ptr, csr_src, dinv, invdeg,
                                             bo, (float*)d_out);
}

// Round 11
// 253.325 us; speedup vs baseline: 5.5152x; 1.0676x over previous
//
#include <hip/hip_runtime.h>
#include <math.h>

#define N_NODES 10000
#define N_EDGES 320000
#define IN_FEATS 512
#define N_UNITS 256
#define OUT_FEATS 64
#define N_HID 5  // hidden Wh layers

typedef __attribute__((ext_vector_type(8))) short bf16x8;
typedef __attribute__((ext_vector_type(4))) float f32x4;

__device__ __forceinline__ unsigned short f2bf(float f) {
    union { float f; unsigned int u; } c; c.f = f;
    unsigned int u = c.u + 0x7FFFu + ((c.u >> 16) & 1u);  // RNE
    return (unsigned short)(u >> 16);
}
__device__ __forceinline__ float bf2f(unsigned int b) {
    union { unsigned int u; float f; } c; c.u = (b & 0xffffu) << 16;
    return c.f;
}

// ---------------- fused setup: deg histogram + h->bf16 + weights->bf16 transposed ----------------

__global__ void k_setup(const int* __restrict__ dst, int* __restrict__ deg,
                        const float* __restrict__ h, unsigned short* __restrict__ hb,
                        const float* __restrict__ W0, const float* __restrict__ Wh,
                        const float* __restrict__ Wo,
                        unsigned short* __restrict__ W0t, unsigned short* __restrict__ Wht,
                        unsigned short* __restrict__ Wot) {
    const int R1 = N_EDGES;
    const int R2 = N_NODES * IN_FEATS / 4;
    const int S0 = IN_FEATS * N_UNITS;
    const int SH = N_HID * N_UNITS * N_UNITS;
    const int SO = N_UNITS * OUT_FEATS;
    int t = blockIdx.x * blockDim.x + threadIdx.x;
    if (t < R1) {
        atomicAdd(&deg[dst[t]], 1);
    } else if (t < R1 + R2) {
        int u = t - R1;
        float4 v = reinterpret_cast<const float4*>(h)[u];
        ushort4 o;
        o.x = f2bf(v.x); o.y = f2bf(v.y); o.z = f2bf(v.z); o.w = f2bf(v.w);
        reinterpret_cast<ushort4*>(hb)[u] = o;
    } else {
        int u = t - R1 - R2;
        if (u < S0) {
            int k = u >> 8, n = u & 255;
            W0t[(size_t)n * IN_FEATS + k] = f2bf(W0[u]);
        } else if (u < S0 + SH) {
            int w = u - S0;
            int l = w >> 16, r = w & 65535;
            int k = r >> 8, n = r & 255;
            Wht[(size_t)l * 65536 + (size_t)n * N_UNITS + k] = f2bf(Wh[w]);
        } else if (u < S0 + SH + SO) {
            int w = u - S0 - SH;
            int k = w >> 6, n = w & 63;
            Wot[(size_t)n * N_UNITS + k] = f2bf(Wo[w]);
        }
    }
}

// ---------------- scan: one 1024-thread block, 10/thread, 3 barriers ----------------

__global__ __launch_bounds__(1024) void k_scan(const int* __restrict__ deg,
                                               int* __restrict__ row_ptr,
                                               int* __restrict__ cursor,
                                               float* __restrict__ dinv,
                                               float* __restrict__ invdeg) {
    __shared__ int wsum[16];
    const int PER = 10;
    int t = threadIdx.x;
    int lane = t & 63, wid = t >> 6;
    int base = t * PER;

    int v[PER];
    int s = 0;
#pragma unroll
    for (int j = 0; j < PER; ++j) {
        int i = base + j;
        int d = (i < N_NODES) ? deg[i] : 0;
        v[j] = s;
        s += d;
    }
    int inc = s;
#pragma unroll
    for (int off = 1; off < 64; off <<= 1) {
        int y = __shfl_up(inc, off);
        if (lane >= off) inc += y;
    }
    if (lane == 63) wsum[wid] = inc;
    __syncthreads();
    if (wid == 0) {
        int w = (lane < 16) ? wsum[lane] : 0;
#pragma unroll
        for (int off = 1; off < 16; off <<= 1) {
            int y = __shfl_up(w, off);
            if (lane >= off) w += y;
        }
        if (lane < 16) wsum[lane] = w;
    }
    __syncthreads();
    int wave_excl = (wid == 0) ? 0 : wsum[wid - 1];
    int thread_excl = wave_excl + (inc - s);

#pragma unroll
    for (int j = 0; j < PER; ++j) {
        int i = base + j;
        if (i < N_NODES) {
            int rp = thread_excl + v[j];
            row_ptr[i] = rp;
            cursor[i]  = rp;
            int d = ((j + 1 < PER) ? v[j + 1] : s) - v[j];
            float dd = (float)(d + 1);
            dinv[i]   = rsqrtf(dd);
            invdeg[i] = 1.0f / dd;
        }
    }
    if (t == 1023) row_ptr[N_NODES] = thread_excl + s;
}

__global__ void k_fill(const int* __restrict__ src, const int* __restrict__ dst,
                       int* __restrict__ cursor, int* __restrict__ csr_src) {
    int e = blockIdx.x * blockDim.x + threadIdx.x;
    if (e < N_EDGES) {
        int p = atomicAdd(&cursor[dst[e]], 1);
        csr_src[p] = src[e];
    }
}

// ---------------- layer-0 GEMM (K=512): 64x64 tile, BK=32, 2-phase dbuf, swizzled LDS ----------------

__global__ __launch_bounds__(256) void k_mgemm(const unsigned short* __restrict__ A,
                                               const unsigned short* __restrict__ Bt,
                                               unsigned short* __restrict__ C,
                                               const int M, const int K, const int Nld) {
    constexpr int BM = 64, BN = 64, BK = 32;
    __shared__ unsigned short As[2][BM * BK];
    __shared__ unsigned short Bs[2][BN * BK];

    const int tid  = threadIdx.x;
    const int wid  = tid >> 6;
    const int lane = tid & 63;
    const int wr   = wid >> 1;
    const int wc   = wid & 1;
    const int brow = blockIdx.y * BM;
    const int bcol = blockIdx.x * BN;

    const int lr = lane & 15;
    const int lk = lane >> 4;

    const int row  = tid >> 2;
    const int slot = tid & 3;
    const int sslot = slot ^ ((row >> 1) & 3);

    int gra = brow + row; if (gra >= M) gra = M - 1;
    const unsigned short* gpa = A + (size_t)gra * K + sslot * 8;
    const unsigned short* gpb = Bt + (size_t)(bcol + row) * K + sslot * 8;

    f32x4 acc[2][2];
#pragma unroll
    for (int m = 0; m < 2; ++m)
#pragma unroll
        for (int n = 0; n < 2; ++n)
            acc[m][n] = (f32x4){0.f, 0.f, 0.f, 0.f};

#define STAGE(buf, k0)                                                                      \
    do {                                                                                    \
        __builtin_amdgcn_global_load_lds(                                                   \
            (const __attribute__((address_space(1))) void*)(gpa + (k0)),                    \
            (__attribute__((address_space(3))) void*)(&As[(buf)][tid * 8]), 16, 0, 0);      \
        __builtin_amdgcn_global_load_lds(                                                   \
            (const __attribute__((address_space(1))) void*)(gpb + (k0)),                    \
            (__attribute__((address_space(3))) void*)(&Bs[(buf)][tid * 8]), 16, 0, 0);      \
    } while (0)

    STAGE(0, 0);
    __syncthreads();

    const int nk = K / BK;
    for (int kt = 0; kt < nk; ++kt) {
        const int cur = kt & 1;
        if (kt + 1 < nk) STAGE(cur ^ 1, (kt + 1) * BK);

        bf16x8 af[2], bfr[2];
#pragma unroll
        for (int m = 0; m < 2; ++m) {
            int ra = wr * 32 + m * 16 + lr;
            af[m] = *reinterpret_cast<const bf16x8*>(&As[cur][ra * BK + (lk ^ ((ra >> 1) & 3)) * 8]);
        }
#pragma unroll
        for (int n = 0; n < 2; ++n) {
            int rb = wc * 32 + n * 16 + lr;
            bfr[n] = *reinterpret_cast<const bf16x8*>(&Bs[cur][rb * BK + (lk ^ ((rb >> 1) & 3)) * 8]);
        }
#pragma unroll
        for (int m = 0; m < 2; ++m)
#pragma unroll
            for (int n = 0; n < 2; ++n)
                acc[m][n] = __builtin_amdgcn_mfma_f32_16x16x32_bf16(af[m], bfr[n], acc[m][n], 0, 0, 0);
        __syncthreads();
    }
#undef STAGE

#pragma unroll
    for (int m = 0; m < 2; ++m) {
#pragma unroll
        for (int r = 0; r < 4; ++r) {
            int orow = brow + wr * 32 + m * 16 + lk * 4 + r;
            if (orow < M) {
#pragma unroll
                for (int n = 0; n < 2; ++n) {
                    int ocol = bcol + wc * 32 + n * 16 + lr;
                    C[(size_t)orow * Nld + ocol] = f2bf(acc[m][n][r]);
                }
            }
        }
    }
}

// ---------------- weight-stationary GEMM (K=256): full-K in LDS, ONE barrier ----------------

__global__ __launch_bounds__(256) void k_wgemm(const unsigned short* __restrict__ A,
                                               const unsigned short* __restrict__ Bt,
                                               unsigned short* __restrict__ C,
                                               const int M, const int Nld) {
    constexpr int K = 256;
    __shared__ unsigned short As[64 * K];
    __shared__ unsigned short Bs[64 * K];

    const int tid  = threadIdx.x;
    const int wid  = tid >> 6;
    const int lane = tid & 63;
    const int lr   = lane & 15;
    const int lk   = lane >> 4;
    const int brow = blockIdx.y * 64;
    const int bcol = blockIdx.x * 64;

#pragma unroll
    for (int p = 0; p < 8; ++p) {
        int i = p * 256 + tid;
        int row = i >> 5, s = i & 31;
        int gr = brow + row; if (gr >= M) gr = M - 1;
        const unsigned short* gp = A + (size_t)gr * K + ((s ^ (row & 7)) * 8);
        __builtin_amdgcn_global_load_lds(
            (const __attribute__((address_space(1))) void*)gp,
            (__attribute__((address_space(3))) void*)(As + i * 8), 16, 0, 0);
    }
#pragma unroll
    for (int p = 0; p < 8; ++p) {
        int i = p * 256 + tid;
        int row = i >> 5, s = i & 31;
        const unsigned short* gp = Bt + (size_t)(bcol + row) * K + ((s ^ (row & 7)) * 8);
        __builtin_amdgcn_global_load_lds(
            (const __attribute__((address_space(1))) void*)gp,
            (__attribute__((address_space(3))) void*)(Bs + i * 8), 16, 0, 0);
    }
    __syncthreads();

    f32x4 acc[4];
#pragma unroll
    for (int n = 0; n < 4; ++n) acc[n] = (f32x4){0.f, 0.f, 0.f, 0.f};

    const int ra = (wid << 4) + lr;
    const unsigned short* Arow = As + ra * K;
    const int e = lr & 7;
#pragma unroll
    for (int kk = 0; kk < 8; ++kk) {
        bf16x8 av = *reinterpret_cast<const bf16x8*>(&Arow[(((kk << 2) + lk) ^ e) * 8]);
#pragma unroll
        for (int n = 0; n < 4; ++n) {
            const unsigned short* Brow = Bs + ((n << 4) + lr) * K;
            bf16x8 bv = *reinterpret_cast<const bf16x8*>(&Brow[(((kk << 2) + lk) ^ e) * 8]);
            acc[n] = __builtin_amdgcn_mfma_f32_16x16x32_bf16(av, bv, acc[n], 0, 0, 0);
        }
    }

#pragma unroll
    for (int n = 0; n < 4; ++n) {
#pragma unroll
        for (int r = 0; r < 4; ++r) {
            int orow = brow + (wid << 4) + (lk << 2) + r;
            if (orow < M) {
                int ocol = bcol + (n << 4) + lr;
                C[(size_t)orow * Nld + ocol] = f2bf(acc[n][r]);
            }
        }
    }
}

// ---------------- CSR aggregation + bias + relu + running JK max ----------------
// 8 nodes / 256-thread block, 32 lanes/node, uint4/lane; UNROLL-8 with index prefetch
// (8 independent 16B loads in flight per lane -> latency-bound gather gets MLP).

__global__ __launch_bounds__(256) void k_agg(const unsigned short* __restrict__ m,
                                             const int* __restrict__ row_ptr,
                                             const int* __restrict__ csr_src,
                                             const float* __restrict__ bias,
                                             unsigned short* __restrict__ x_out,
                                             unsigned short* __restrict__ jk,
                                             int init_jk) {
    int half = threadIdx.x >> 5;
    int lane = threadIdx.x & 31;
    int n = blockIdx.x * 8 + half;
    int s = row_ptr[n], e = row_ptr[n + 1];
    const uint4* mv = (const uint4*)m;

    float a[8];
#pragma unroll
    for (int j = 0; j < 8; ++j) a[j] = 0.f;

#define ACC8(u)                                        \
    do {                                               \
        a[0] += bf2f((u).x); a[1] += bf2f((u).x >> 16);\
        a[2] += bf2f((u).y); a[3] += bf2f((u).y >> 16);\
        a[4] += bf2f((u).z); a[5] += bf2f((u).z >> 16);\
        a[6] += bf2f((u).w); a[7] += bf2f((u).w >> 16);\
    } while (0)

    int i = s;
    for (; i + 7 < e; i += 8) {
        int idx[8];
#pragma unroll
        for (int q = 0; q < 8; ++q) idx[q] = csr_src[i + q];
        uint4 u[8];
#pragma unroll
        for (int q = 0; q < 8; ++q) u[q] = mv[(size_t)idx[q] * 32 + lane];
#pragma unroll
        for (int q = 0; q < 8; ++q) ACC8(u[q]);
    }
    for (; i < e; ++i) {
        uint4 u = mv[(size_t)csr_src[i] * 32 + lane];
        ACC8(u);
    }
#undef ACC8

    float4 b0 = ((const float4*)bias)[lane * 2];
    float4 b1 = ((const float4*)bias)[lane * 2 + 1];
    unsigned int hh[8];
    hh[0] = f2bf(fmaxf(a[0] + b0.x, 0.f));
    hh[1] = f2bf(fmaxf(a[1] + b0.y, 0.f));
    hh[2] = f2bf(fmaxf(a[2] + b0.z, 0.f));
    hh[3] = f2bf(fmaxf(a[3] + b0.w, 0.f));
    hh[4] = f2bf(fmaxf(a[4] + b1.x, 0.f));
    hh[5] = f2bf(fmaxf(a[5] + b1.y, 0.f));
    hh[6] = f2bf(fmaxf(a[6] + b1.z, 0.f));
    hh[7] = f2bf(fmaxf(a[7] + b1.w, 0.f));
    uint4 o;
    o.x = hh[0] | (hh[1] << 16);
    o.y = hh[2] | (hh[3] << 16);
    o.z = hh[4] | (hh[5] << 16);
    o.w = hh[6] | (hh[7] << 16);

    size_t idx = (size_t)n * 32 + lane;
    ((uint4*)x_out)[idx] = o;
    if (init_jk) {
        ((uint4*)jk)[idx] = o;
    } else {
        uint4 j = ((const uint4*)jk)[idx];
        auto mx2 = [](unsigned int nw, unsigned int od) {
            unsigned int lo_n = nw & 0xffffu, lo_o = od & 0xffffu;
            unsigned int hi_n = nw >> 16,     hi_o = od >> 16;
            unsigned int lo = lo_n > lo_o ? lo_n : lo_o;
            unsigned int hi = hi_n > hi_o ? hi_n : hi_o;
            return lo | (hi << 16);
        };
        uint4 w;
        w.x = mx2(o.x, j.x); w.y = mx2(o.y, j.y);
        w.z = mx2(o.z, j.z); w.w = mx2(o.w, j.w);
        ((uint4*)jk)[idx] = w;
    }
}

// ---------------- final GCN-norm agg + self loop + bias + log_softmax ----------------
// 2 nodes per wave, uint loads, UNROLL-4 with index/coef prefetch.

__global__ __launch_bounds__(256) void k_final(const unsigned short* __restrict__ mf,
                                               const int* __restrict__ row_ptr,
                                               const int* __restrict__ csr_src,
                                               const float* __restrict__ dinv,
                                               const float* __restrict__ invdeg,
                                               const float* __restrict__ bo,
                                               float* __restrict__ out) {
    int halfw = threadIdx.x >> 5;
    int wl = threadIdx.x & 31;
    const unsigned int* mfu = (const unsigned int*)mf;
    int n = blockIdx.x * 8 + halfw;
    int s = row_ptr[n], e = row_ptr[n + 1];

    float a0 = 0.f, a1 = 0.f;
    int i = s;
    for (; i + 3 < e; i += 4) {
        int i0 = csr_src[i], i1 = csr_src[i + 1], i2 = csr_src[i + 2], i3 = csr_src[i + 3];
        unsigned int u0 = mfu[(size_t)i0 * 32 + wl];
        unsigned int u1 = mfu[(size_t)i1 * 32 + wl];
        unsigned int u2 = mfu[(size_t)i2 * 32 + wl];
        unsigned int u3 = mfu[(size_t)i3 * 32 + wl];
        float d0 = dinv[i0], d1 = dinv[i1], d2 = dinv[i2], d3 = dinv[i3];
        a0 += bf2f(u0) * d0 + bf2f(u1) * d1 + bf2f(u2) * d2 + bf2f(u3) * d3;
        a1 += bf2f(u0 >> 16) * d0 + bf2f(u1 >> 16) * d1 + bf2f(u2 >> 16) * d2 + bf2f(u3 >> 16) * d3;
    }
    for (; i < e; ++i) {
        int sr = csr_src[i];
        unsigned int u = mfu[(size_t)sr * 32 + wl];
        float dv = dinv[sr];
        a0 += bf2f(u) * dv;
        a1 += bf2f(u >> 16) * dv;
    }
    float dn = dinv[n];
    a0 *= dn; a1 *= dn;
    unsigned int un = mfu[(size_t)n * 32 + wl];
    float idg = invdeg[n];
    float2 bo2 = ((const float2*)bo)[wl];
    a0 += bf2f(un) * idg + bo2.x;
    a1 += bf2f(un >> 16) * idg + bo2.y;

    float mx = fmaxf(a0, a1);
#pragma unroll
    for (int off = 16; off; off >>= 1) mx = fmaxf(mx, __shfl_xor(mx, off));
    float e0 = __expf(a0 - mx), e1 = __expf(a1 - mx);
    float sum = e0 + e1;
#pragma unroll
    for (int off = 16; off; off >>= 1) sum += __shfl_xor(sum, off);
    float ls = __logf(sum);
    float2 r;
    r.x = a0 - mx - ls;
    r.y = a1 - mx - ls;
    ((float2*)out)[(size_t)n * 32 + wl] = r;
}

// ---------------- launch ----------------

extern "C" void kernel_launch(void* const* d_in, const int* in_sizes, int n_in,
                              void* d_out, int out_size, void* d_ws, size_t ws_size,
                              hipStream_t stream) {
    const float* h  = (const float*)d_in[0];
    const int*   ei = (const int*)d_in[1];
    const float* W0 = (const float*)d_in[2];
    const float* b0 = (const float*)d_in[3];
    const float* Wh = (const float*)d_in[4];
    const float* bh = (const float*)d_in[5];
    const float* Wo = (const float*)d_in[6];
    const float* bo = (const float*)d_in[7];

    const int* src = ei;
    const int* dst = ei + N_EDGES;

    char* p = (char*)d_ws;
    auto carve = [&](size_t bytes) {
        char* r = p;
        p += (bytes + 255) & ~(size_t)255;
        return r;
    };
    int*   deg     = (int*)  carve(N_NODES * 4);
    int*   row_ptr = (int*)  carve((N_NODES + 1) * 4);
    int*   cursor  = (int*)  carve(N_NODES * 4);
    int*   csr_src = (int*)  carve(N_EDGES * 4);
    float* dinv    = (float*)carve(N_NODES * 4);
    float* invdeg  = (float*)carve(N_NODES * 4);
    unsigned short* hb  = (unsigned short*)carve((size_t)N_NODES * IN_FEATS * 2);
    unsigned short* W0t = (unsigned short*)carve((size_t)IN_FEATS * N_UNITS * 2);
    unsigned short* Wht = (unsigned short*)carve((size_t)N_HID * N_UNITS * N_UNITS * 2);
    unsigned short* Wot = (unsigned short*)carve((size_t)N_UNITS * OUT_FEATS * 2);
    unsigned short* m   = (unsigned short*)carve((size_t)N_NODES * N_UNITS * 2);
    unsigned short* x   = (unsigned short*)carve((size_t)N_NODES * N_UNITS * 2);
    unsigned short* jk  = (unsigned short*)carve((size_t)N_NODES * N_UNITS * 2);
    unsigned short* mf  = (unsigned short*)carve((size_t)N_NODES * OUT_FEATS * 2);

    hipMemsetAsync(deg, 0, N_NODES * 4, stream);
    {
        const int total = N_EDGES + N_NODES * IN_FEATS / 4 +
                          IN_FEATS * N_UNITS + N_HID * N_UNITS * N_UNITS + N_UNITS * OUT_FEATS;
        k_setup<<<(total + 255) / 256, 256, 0, stream>>>(dst, deg, h, hb, W0, Wh, Wo,
                                                         W0t, Wht, Wot);
    }
    k_scan<<<1, 1024, 0, stream>>>(deg, row_ptr, cursor, dinv, invdeg);
    k_fill<<<(N_EDGES + 255) / 256, 256, 0, stream>>>(src, dst, cursor, csr_src);

    const int GBM = (N_NODES + 63) / 64;  // 157

    // layer 0: m = hb @ W0t^T (K=512)
    {
        dim3 g(N_UNITS / 64, GBM);
        k_mgemm<<<g, 256, 0, stream>>>(hb, W0t, m, N_NODES, IN_FEATS, N_UNITS);
    }
    k_agg<<<N_NODES / 8, 256, 0, stream>>>(m, row_ptr, csr_src, b0, x, jk, 1);

    // hidden layers: weight-stationary K=256
    for (int l = 0; l < N_HID; ++l) {
        dim3 g(N_UNITS / 64, GBM);
        k_wgemm<<<g, 256, 0, stream>>>(x, Wht + (size_t)l * N_UNITS * N_UNITS, m,
                                       N_NODES, N_UNITS);
        k_agg<<<N_NODES / 8, 256, 0, stream>>>(m, row_ptr, csr_src, bh + (size_t)l * N_UNITS,
                                               x, jk, 0);
    }

    // final: mf = jk @ Wot^T (K=256, N=64)
    {
        dim3 g(1, GBM);
        k_wgemm<<<g, 256, 0, stream>>>(jk, Wot, mf, N_NODES, OUT_FEATS);
    }
    k_final<<<N_NODES / 8, 256, 0, stream>>>(mf, row_ptr, csr_src, dinv, invdeg,
                                             bo, (float*)d_out);
}